// Round 3
// baseline (160.940 us; speedup 1.0000x reference)
//
#include <hip/hip_runtime.h>

// Linear attention via bf16 MFMA, 3 kernels:
//   A: part[c][b][v][d] (bf16) = sum_{k in chunk c} V[b,k,v]*(relu(K[b,k,d])+eps)
//   R: kvb[b][v][d] (bf16) = sum_c part[c][b][v][d]   (fp32 accumulate)
//   B: out[b][q][v] = sum_d (relu(Q[b,q,d])+eps) * kvb[b][v][d]
// mfma_f32_16x16x32_bf16 everywhere; LDS tiles [row][k] k-contiguous with 16B
// XOR swizzle (chunk ^= row&7). R2 focus: occupancy (2 blk/CU kvt, 4 blk/CU out)
// + bf16 partials + coalesced kvt epilogue via LDS bounce.

#define BB 8
#define SS 4096
#define DD 256
#define DDV 256
#define EPSF 1e-6f

typedef short bf16x8 __attribute__((ext_vector_type(8)));
typedef float f32x4 __attribute__((ext_vector_type(4)));

__device__ __forceinline__ unsigned int f2bf(float f) {
  unsigned int u = __float_as_uint(f);
  u += 0x7FFF + ((u >> 16) & 1);   // RNE
  return u >> 16;
}
__device__ __forceinline__ unsigned int pack2(float a, float b) {
  return f2bf(a) | (f2bf(b) << 16);
}
__device__ __forceinline__ float bf2f(ushort h) {
  return __uint_as_float(((unsigned int)h) << 16);
}

// ---------------- Kernel A: KVT partials (bf16) ----------------
// grid (2 /*v-tile*/, nchunk, BB), block 512, 2 blocks/CU.
__global__ __launch_bounds__(512, 4) void kvt_kernel(
    const float* __restrict__ K, const float* __restrict__ V,
    ushort* __restrict__ part, int kchunk) {
  const int vt    = blockIdx.x;
  const int chunk = blockIdx.y;
  const int b     = blockIdx.z;
  const int k0blk = chunk * kchunk;

  __shared__ __align__(16) ushort smem[128 * 64 + 256 * 64];  // 48 KB
  ushort* Vt = smem;             // [v 128][k 64] swizzled
  ushort* Kt = smem + 128 * 64;  // [d 256][k 64] swizzled

  const int tid  = threadIdx.x;
  const int lane = tid & 63;
  const int w    = tid >> 6;   // 0..7
  const int wv   = w >> 2;     // 0..1 (v dir)
  const int wd   = w & 3;      // 0..3 (d dir)

  f32x4 acc[4][4];
  #pragma unroll
  for (int i = 0; i < 4; i++)
    #pragma unroll
    for (int j = 0; j < 4; j++)
      acc[i][j] = (f32x4){0.f, 0.f, 0.f, 0.f};

  const float* Vb = V + (size_t)b * SS * DDV + vt * 128;
  const float* Kb = K + (size_t)b * SS * DD;

  for (int kk = 0; kk < kchunk; kk += 64) {
    // V tile: 128 v-rows x 8 k-octets (transpose via coalesced column loads)
    {
      const int r = tid & 127;
      const int ob = tid >> 7;   // 0..3
      #pragma unroll
      for (int p = 0; p < 2; p++) {
        const int o = ob + p * 4;
        float f[8];
        #pragma unroll
        for (int j = 0; j < 8; j++)
          f[j] = Vb[(size_t)(k0blk + kk + o * 8 + j) * DDV + r];
        uint4 wq;
        wq.x = pack2(f[0], f[1]); wq.y = pack2(f[2], f[3]);
        wq.z = pack2(f[4], f[5]); wq.w = pack2(f[6], f[7]);
        *(uint4*)&Vt[r * 64 + (o ^ (r & 7)) * 8] = wq;
      }
    }
    // K tile: 256 d-rows x 8 k-octets, relu+eps fused
    {
      const int r = tid & 255;
      const int ob = tid >> 8;   // 0..1
      #pragma unroll
      for (int p = 0; p < 4; p++) {
        const int o = ob + p * 2;
        float f[8];
        #pragma unroll
        for (int j = 0; j < 8; j++)
          f[j] = Kb[(size_t)(k0blk + kk + o * 8 + j) * DD + r];
        #pragma unroll
        for (int j = 0; j < 8; j++) f[j] = fmaxf(f[j], 0.0f) + EPSF;
        uint4 wq;
        wq.x = pack2(f[0], f[1]); wq.y = pack2(f[2], f[3]);
        wq.z = pack2(f[4], f[5]); wq.w = pack2(f[6], f[7]);
        *(uint4*)&Kt[r * 64 + (o ^ (r & 7)) * 8] = wq;
      }
    }
    __syncthreads();
    #pragma unroll
    for (int ks = 0; ks < 2; ks++) {
      const int oct = ks * 4 + (lane >> 4);
      bf16x8 af[4], bfr[4];
      #pragma unroll
      for (int i = 0; i < 4; i++) {
        const int row = wv * 64 + i * 16 + (lane & 15);
        af[i] = *(const bf16x8*)&Vt[row * 64 + (oct ^ (row & 7)) * 8];
      }
      #pragma unroll
      for (int j = 0; j < 4; j++) {
        const int row = wd * 64 + j * 16 + (lane & 15);
        bfr[j] = *(const bf16x8*)&Kt[row * 64 + (oct ^ (row & 7)) * 8];
      }
      #pragma unroll
      for (int i = 0; i < 4; i++)
        #pragma unroll
        for (int j = 0; j < 4; j++)
          acc[i][j] = __builtin_amdgcn_mfma_f32_16x16x32_bf16(af[i], bfr[j], acc[i][j], 0, 0, 0);
    }
    __syncthreads();
  }

  // Epilogue: bounce acc through LDS (bf16, [vloc 64][d 264]) -> coalesced stores.
  ushort* tr = smem;   // 64*264*2 B = 33 KB, fits
  ushort* pb = part + ((size_t)chunk * BB + b) * (DD * DDV) + (size_t)vt * 128 * DD;
  const int quad = lane >> 4;
  #pragma unroll
  for (int p = 0; p < 2; p++) {
    if (wv == p) {
      #pragma unroll
      for (int i = 0; i < 4; i++)
        #pragma unroll
        for (int j = 0; j < 4; j++) {
          const int d = wd * 64 + j * 16 + (lane & 15);
          #pragma unroll
          for (int r = 0; r < 4; r++) {
            const int vloc = i * 16 + quad * 4 + r;
            tr[vloc * 264 + d] = (ushort)f2bf(acc[i][j][r]);
          }
        }
    }
    __syncthreads();
    {
      const int c = tid & 31;
      #pragma unroll
      for (int ro = 0; ro < 4; ro++) {
        const int vloc = ro * 16 + (tid >> 5);
        uint4 val = *(const uint4*)&tr[vloc * 264 + c * 8];
        *(uint4*)&pb[(size_t)(p * 64 + vloc) * DD + c * 8] = val;
      }
    }
    __syncthreads();
  }
}

// ---------------- Kernel R: reduce bf16 partials -> bf16 KVT ----------------
// grid 512, block 256; thread handles 4 consecutive elements (uint2).
__global__ __launch_bounds__(256) void reduce_kernel(
    const ushort* __restrict__ part, ushort* __restrict__ kvb, int nchunk) {
  const size_t N = (size_t)BB * DD * DDV;   // 524288
  const size_t i4 = ((size_t)blockIdx.x * 256 + threadIdx.x) * 4;
  float s0 = 0.f, s1 = 0.f, s2 = 0.f, s3 = 0.f;
  for (int c = 0; c < nchunk; c++) {
    uint2 p = *(const uint2*)&part[(size_t)c * N + i4];
    s0 += bf2f((ushort)(p.x & 0xFFFF)); s1 += bf2f((ushort)(p.x >> 16));
    s2 += bf2f((ushort)(p.y & 0xFFFF)); s3 += bf2f((ushort)(p.y >> 16));
  }
  uint2 o;
  o.x = pack2(s0, s1);
  o.y = pack2(s2, s3);
  *(uint2*)&kvb[i4] = o;
}

// ---------------- Kernel B: out = (relu(Q)+eps) @ KVT^T ----------------
// grid (64 /*q-tile*/, 2 /*v-tile*/, BB) = 1024 blocks, block 256, 4 blocks/CU.
__global__ __launch_bounds__(256, 4) void out_kernel(
    const float* __restrict__ Q, const ushort* __restrict__ kvb,
    float* __restrict__ out) {
  const int qt = blockIdx.x;
  const int vt = blockIdx.y;
  const int b  = blockIdx.z;
  const int q0 = qt * 64;

  __shared__ __align__(16) ushort Qs[64 * 64];    // 8 KB
  __shared__ __align__(16) ushort KVs[128 * 64];  // 16 KB

  const int tid  = threadIdx.x;
  const int lane = tid & 63;
  const int w    = tid >> 6;   // 0..3
  const int wq   = w >> 1;     // 0..1 (q dir, 32 each)
  const int wvv  = w & 1;      // 0..1 (v dir, 64 each)

  f32x4 acc[2][4];
  #pragma unroll
  for (int i = 0; i < 2; i++)
    #pragma unroll
    for (int j = 0; j < 4; j++)
      acc[i][j] = (f32x4){0.f, 0.f, 0.f, 0.f};

  const float* Qb = Q + ((size_t)b * SS + q0) * DD;
  const ushort* KVb = kvb + (size_t)b * DD * DDV + (size_t)vt * 128 * DD;

  for (int dc = 0; dc < DD; dc += 64) {
    // Q tile: 64 q x 64 d, float4 loads, relu+eps+cvt
    {
      const int c = tid & 15;
      #pragma unroll
      for (int p = 0; p < 4; p++) {
        const int q = p * 16 + (tid >> 4);
        float4 f = *(const float4*)&Qb[(size_t)q * DD + dc + c * 4];
        f.x = fmaxf(f.x, 0.f) + EPSF; f.y = fmaxf(f.y, 0.f) + EPSF;
        f.z = fmaxf(f.z, 0.f) + EPSF; f.w = fmaxf(f.w, 0.f) + EPSF;
        uint2 wp; wp.x = pack2(f.x, f.y); wp.y = pack2(f.z, f.w);
        *(uint2*)&Qs[q * 64 + (((c >> 1) ^ (q & 7)) << 3) + ((c & 1) << 2)] = wp;
      }
    }
    // KV tile: 128 v x 64 d bf16, uint4 loads, source-permuted for swizzle
    {
      const int c = tid & 7;
      #pragma unroll
      for (int p = 0; p < 4; p++) {
        const int row = p * 32 + (tid >> 3);
        const int o = c ^ (row & 7);
        uint4 val = *(const uint4*)&KVb[(size_t)row * DD + dc + o * 8];
        *(uint4*)&KVs[row * 64 + c * 8] = val;
      }
    }
    __syncthreads();
    #pragma unroll
    for (int ks = 0; ks < 2; ks++) {
      const int oct = ks * 4 + (lane >> 4);
      bf16x8 af[2], bfr[4];
      #pragma unroll
      for (int i = 0; i < 2; i++) {
        const int row = wq * 32 + i * 16 + (lane & 15);
        af[i] = *(const bf16x8*)&Qs[row * 64 + ((oct ^ (row & 7)) << 3)];
      }
      #pragma unroll
      for (int j = 0; j < 4; j++) {
        const int row = wvv * 64 + j * 16 + (lane & 15);
        bfr[j] = *(const bf16x8*)&KVs[row * 64 + ((oct ^ (row & 7)) << 3)];
      }
      #pragma unroll
      for (int i = 0; i < 2; i++)
        #pragma unroll
        for (int j = 0; j < 4; j++)
          acc[i][j] = __builtin_amdgcn_mfma_f32_16x16x32_bf16(af[i], bfr[j], acc[i][j], 0, 0, 0);
    }
    __syncthreads();
  }

  float* ob = out + ((size_t)b * SS + q0) * DDV + (size_t)vt * 128;
  const int quad = lane >> 4;
  #pragma unroll
  for (int i = 0; i < 2; i++) {
    const int qrow = wq * 32 + i * 16 + quad * 4;
    #pragma unroll
    for (int j = 0; j < 4; j++) {
      const int v = wvv * 64 + j * 16 + (lane & 15);
      #pragma unroll
      for (int r = 0; r < 4; r++)
        ob[(size_t)(qrow + r) * DDV + v] = acc[i][j][r];
    }
  }
}

extern "C" void kernel_launch(void* const* d_in, const int* in_sizes, int n_in,
                              void* d_out, int out_size, void* d_ws, size_t ws_size,
                              hipStream_t stream) {
  const float* Q = (const float*)d_in[0];
  const float* K = (const float*)d_in[1];
  const float* V = (const float*)d_in[2];
  float* out = (float*)d_out;

  const size_t N = (size_t)BB * DD * DDV;  // 524288 elements
  int nchunk = 32;
  while (nchunk > 1 && ((size_t)nchunk * N + N) * 2 > ws_size) nchunk >>= 1;
  const int kchunk = SS / nchunk;

  ushort* part = (ushort*)d_ws;
  ushort* kvb  = part + (size_t)nchunk * N;

  kvt_kernel<<<dim3(2, nchunk, BB), 512, 0, stream>>>(K, V, part, kchunk);
  reduce_kernel<<<dim3(512), 256, 0, stream>>>(part, kvb, nchunk);
  out_kernel<<<dim3(64, 2, BB), 256, 0, stream>>>(Q, kvb, out);
}

// Round 4
// 155.469 us; speedup vs baseline: 1.0352x; 1.0352x over previous
//
#include <hip/hip_runtime.h>

// Linear attention via bf16 MFMA, 3 kernels:
//   A: part[c][b][v][d] (bf16) = sum_{k in chunk c} V[b,k,v]*(relu(K[b,k,d])+eps)
//      FULL 256x256 tile per block -> K,V each read exactly once.
//   R: kvb[b][v][d] (bf16) = sum_c part[c][b][v][d]  (fp32 accumulate)
//   B: out[b][q][v] = sum_d (relu(Q[b,q,d])+eps)*kvb[b][v][d], 64q x 256v tile
//      -> Q read exactly once (kv tile is L2-resident).
// mfma_f32_16x16x32_bf16; LDS tiles [row][k] k-contiguous, 16B XOR swizzle.

#define BB 8
#define SS 4096
#define DD 256
#define DDV 256
#define EPSF 1e-6f

typedef short bf16x8 __attribute__((ext_vector_type(8)));
typedef float f32x4 __attribute__((ext_vector_type(4)));

__device__ __forceinline__ unsigned int f2bf(float f) {
  unsigned int u = __float_as_uint(f);
  u += 0x7FFF + ((u >> 16) & 1);   // RNE
  return u >> 16;
}
__device__ __forceinline__ unsigned int pack2(float a, float b) {
  return f2bf(a) | (f2bf(b) << 16);
}
__device__ __forceinline__ float bf2f(ushort h) {
  return __uint_as_float(((unsigned int)h) << 16);
}

// ---------------- Kernel A: KVT partials (bf16), full 256x256 tile ----------
// grid (nchunk, BB), block 512. LDS: staging 64 KB, epilogue bounce 128 KB.
__global__ __launch_bounds__(512) void kvt_kernel(
    const float* __restrict__ K, const float* __restrict__ V,
    ushort* __restrict__ part, int kchunk) {
  const int sc = blockIdx.x;   // split-K chunk
  const int b  = blockIdx.y;
  const int k0 = sc * kchunk;

  __shared__ __align__(16) ushort smem[256 * 256];  // 128 KB (union)
  ushort* Vt = smem;               // [v 256][k 64] swizzled, 32 KB
  ushort* Kt = smem + 256 * 64;    // [d 256][k 64] swizzled, 32 KB

  const int tid  = threadIdx.x;
  const int lane = tid & 63;
  const int w    = tid >> 6;   // 0..7
  const int wv   = w >> 2;     // 0..1 : v half (128 rows)
  const int wd   = w & 3;      // 0..3 : d quarter (64 cols)

  f32x4 acc[8][4];
  #pragma unroll
  for (int i = 0; i < 8; i++)
    #pragma unroll
    for (int j = 0; j < 4; j++)
      acc[i][j] = (f32x4){0.f, 0.f, 0.f, 0.f};

  const float* Vb = V + (size_t)b * SS * DDV;
  const float* Kb = K + (size_t)b * SS * DD;

  for (int kk = 0; kk < kchunk; kk += 64) {
    const int r  = tid & 255;    // row (v or d)
    const int ob = tid >> 8;     // 0..1
    // V tile: 256 v-rows x 8 k-octets (transpose via coalesced column loads)
    #pragma unroll
    for (int p = 0; p < 4; p++) {
      const int o = p * 2 + ob;
      float f[8];
      #pragma unroll
      for (int j = 0; j < 8; j++)
        f[j] = Vb[(size_t)(k0 + kk + o * 8 + j) * DDV + r];
      uint4 wq;
      wq.x = pack2(f[0], f[1]); wq.y = pack2(f[2], f[3]);
      wq.z = pack2(f[4], f[5]); wq.w = pack2(f[6], f[7]);
      *(uint4*)&Vt[r * 64 + (o ^ (r & 7)) * 8] = wq;
    }
    // K tile: 256 d-rows x 8 k-octets, relu+eps fused
    #pragma unroll
    for (int p = 0; p < 4; p++) {
      const int o = p * 2 + ob;
      float f[8];
      #pragma unroll
      for (int j = 0; j < 8; j++)
        f[j] = Kb[(size_t)(k0 + kk + o * 8 + j) * DD + r];
      #pragma unroll
      for (int j = 0; j < 8; j++) f[j] = fmaxf(f[j], 0.0f) + EPSF;
      uint4 wq;
      wq.x = pack2(f[0], f[1]); wq.y = pack2(f[2], f[3]);
      wq.z = pack2(f[4], f[5]); wq.w = pack2(f[6], f[7]);
      *(uint4*)&Kt[r * 64 + (o ^ (r & 7)) * 8] = wq;
    }
    __syncthreads();
    #pragma unroll
    for (int ks = 0; ks < 2; ks++) {
      const int oct = ks * 4 + (lane >> 4);
      bf16x8 af[8], bfr[4];
      #pragma unroll
      for (int i = 0; i < 8; i++) {
        const int row = wv * 128 + i * 16 + (lane & 15);
        af[i] = *(const bf16x8*)&Vt[row * 64 + ((oct ^ (row & 7)) << 3)];
      }
      #pragma unroll
      for (int j = 0; j < 4; j++) {
        const int row = wd * 64 + j * 16 + (lane & 15);
        bfr[j] = *(const bf16x8*)&Kt[row * 64 + ((oct ^ (row & 7)) << 3)];
      }
      #pragma unroll
      for (int i = 0; i < 8; i++)
        #pragma unroll
        for (int j = 0; j < 4; j++)
          acc[i][j] = __builtin_amdgcn_mfma_f32_16x16x32_bf16(af[i], bfr[j], acc[i][j], 0, 0, 0);
    }
    __syncthreads();
  }

  // Epilogue: bounce full 256x256 bf16 tile through LDS (swizzled), then
  // stream out coalesced dwordx4.
  const int quad = lane >> 4;
  #pragma unroll
  for (int i = 0; i < 8; i++)
    #pragma unroll
    for (int j = 0; j < 4; j++) {
      const int d = wd * 64 + j * 16 + (lane & 15);
      #pragma unroll
      for (int r = 0; r < 4; r++) {
        const int v = wv * 128 + i * 16 + quad * 4 + r;
        smem[v * 256 + ((((d >> 3) ^ (v & 7)) << 3) | (d & 7))] = (ushort)f2bf(acc[i][j][r]);
      }
    }
  __syncthreads();
  ushort* pb = part + ((size_t)sc * BB + b) * (DD * DDV);
  {
    const int c = tid & 31;          // 16B chunk within row
    const int r0 = tid >> 5;         // 0..15
    #pragma unroll
    for (int p = 0; p < 16; p++) {
      const int row = p * 16 + r0;
      uint4 val = *(const uint4*)&smem[row * 256 + ((c ^ (row & 7)) << 3)];
      *(uint4*)&pb[(size_t)row * DD + c * 8] = val;
    }
  }
}

// ---------------- Kernel R: reduce bf16 partials -> bf16 KVT ----------------
__global__ __launch_bounds__(256) void reduce_kernel(
    const ushort* __restrict__ part, ushort* __restrict__ kvb, int nchunk) {
  const size_t N = (size_t)BB * DD * DDV;   // 524288
  const size_t i4 = ((size_t)blockIdx.x * 256 + threadIdx.x) * 4;
  float s0 = 0.f, s1 = 0.f, s2 = 0.f, s3 = 0.f;
  for (int c = 0; c < nchunk; c++) {
    uint2 p = *(const uint2*)&part[(size_t)c * N + i4];
    s0 += bf2f((ushort)(p.x & 0xFFFF)); s1 += bf2f((ushort)(p.x >> 16));
    s2 += bf2f((ushort)(p.y & 0xFFFF)); s3 += bf2f((ushort)(p.y >> 16));
  }
  uint2 o;
  o.x = pack2(s0, s1);
  o.y = pack2(s2, s3);
  *(uint2*)&kvb[i4] = o;
}

// ---------------- Kernel B: out = (relu(Q)+eps) @ KVT^T ----------------
// grid (64 q-tiles, BB), block 256, 64q x 256v tile (Q read once).
__global__ __launch_bounds__(256, 3) void out_kernel(
    const float* __restrict__ Q, const ushort* __restrict__ kvb,
    float* __restrict__ out) {
  const int qt = blockIdx.x;
  const int b  = blockIdx.y;
  const int q0 = qt * 64;

  __shared__ __align__(16) ushort Qs[64 * 64];    //  8 KB
  __shared__ __align__(16) ushort KVs[256 * 64];  // 32 KB

  const int tid  = threadIdx.x;
  const int lane = tid & 63;
  const int w    = tid >> 6;   // 0..3
  const int wq   = w >> 1;     // 0..1 : q half (32 rows)
  const int wvv  = w & 1;      // 0..1 : v half (128 cols)

  f32x4 acc[2][8];
  #pragma unroll
  for (int i = 0; i < 2; i++)
    #pragma unroll
    for (int j = 0; j < 8; j++)
      acc[i][j] = (f32x4){0.f, 0.f, 0.f, 0.f};

  const float* Qb = Q + ((size_t)b * SS + q0) * DD;
  const ushort* KVb = kvb + (size_t)b * DD * DDV;

  for (int dc = 0; dc < DD; dc += 64) {
    // Q tile: 64 q x 64 d, float4 loads, relu+eps+cvt
    {
      const int c = tid & 15;
      #pragma unroll
      for (int p = 0; p < 4; p++) {
        const int q = p * 16 + (tid >> 4);
        float4 f = *(const float4*)&Qb[(size_t)q * DD + dc + c * 4];
        f.x = fmaxf(f.x, 0.f) + EPSF; f.y = fmaxf(f.y, 0.f) + EPSF;
        f.z = fmaxf(f.z, 0.f) + EPSF; f.w = fmaxf(f.w, 0.f) + EPSF;
        uint2 wp; wp.x = pack2(f.x, f.y); wp.y = pack2(f.z, f.w);
        *(uint2*)&Qs[q * 64 + (((c >> 1) ^ (q & 7)) << 3) + ((c & 1) << 2)] = wp;
      }
    }
    // KV tile: 256 v x 64 d bf16, uint4 loads, source-permuted for swizzle
    {
      const int c = tid & 7;
      #pragma unroll
      for (int p = 0; p < 8; p++) {
        const int row = p * 32 + (tid >> 3);
        const int o = c ^ (row & 7);
        uint4 val = *(const uint4*)&KVb[(size_t)row * DD + dc + o * 8];
        *(uint4*)&KVs[row * 64 + c * 8] = val;
      }
    }
    __syncthreads();
    #pragma unroll
    for (int ks = 0; ks < 2; ks++) {
      const int oct = ks * 4 + (lane >> 4);
      bf16x8 af[2], bfr[8];
      #pragma unroll
      for (int i = 0; i < 2; i++) {
        const int row = wq * 32 + i * 16 + (lane & 15);
        af[i] = *(const bf16x8*)&Qs[row * 64 + ((oct ^ (row & 7)) << 3)];
      }
      #pragma unroll
      for (int j = 0; j < 8; j++) {
        const int row = wvv * 128 + j * 16 + (lane & 15);
        bfr[j] = *(const bf16x8*)&KVs[row * 64 + ((oct ^ (row & 7)) << 3)];
      }
      #pragma unroll
      for (int i = 0; i < 2; i++)
        #pragma unroll
        for (int j = 0; j < 8; j++)
          acc[i][j] = __builtin_amdgcn_mfma_f32_16x16x32_bf16(af[i], bfr[j], acc[i][j], 0, 0, 0);
    }
    __syncthreads();
  }

  float* ob = out + ((size_t)b * SS + q0) * DDV;
  const int quad = lane >> 4;
  #pragma unroll
  for (int i = 0; i < 2; i++) {
    const int qrow = wq * 32 + i * 16 + quad * 4;
    #pragma unroll
    for (int j = 0; j < 8; j++) {
      const int v = wvv * 128 + j * 16 + (lane & 15);
      #pragma unroll
      for (int r = 0; r < 4; r++)
        ob[(size_t)(qrow + r) * DDV + v] = acc[i][j][r];
    }
  }
}

extern "C" void kernel_launch(void* const* d_in, const int* in_sizes, int n_in,
                              void* d_out, int out_size, void* d_ws, size_t ws_size,
                              hipStream_t stream) {
  const float* Q = (const float*)d_in[0];
  const float* K = (const float*)d_in[1];
  const float* V = (const float*)d_in[2];
  float* out = (float*)d_out;

  const size_t N = (size_t)BB * DD * DDV;  // 524288 elements
  int nchunk = 32;
  while (nchunk > 1 && ((size_t)nchunk * N + N) * 2 > ws_size) nchunk >>= 1;
  const int kchunk = SS / nchunk;

  ushort* part = (ushort*)d_ws;
  ushort* kvb  = part + (size_t)nchunk * N;

  kvt_kernel<<<dim3(nchunk, BB), 512, 0, stream>>>(K, V, part, kchunk);
  reduce_kernel<<<dim3(512), 256, 0, stream>>>(part, kvb, nchunk);
  out_kernel<<<dim3(64, BB), 256, 0, stream>>>(Q, kvb, out);
}